// Round 2
// baseline (817.658 us; speedup 1.0000x reference)
//
#include <hip/hip_runtime.h>

// SOCA forward: cov-pool -> Newton-Schulz sqrtm (5 iters) -> SE gate -> scale.
// B=16, C=128, H=W=192, M=36864, RED=8 (cr=16).

#define BATCH 16
#define CHN   128
#define MLEN  36864

typedef short bf16x8 __attribute__((ext_vector_type(8)));
typedef float f32x4  __attribute__((ext_vector_type(4)));

__device__ __forceinline__ ushort f2bf(float f) {
    unsigned u = __float_as_uint(f);
    u = (u + 0x7FFFu + ((u >> 16) & 1u)) >> 16;   // RNE
    return (ushort)u;
}
__device__ __forceinline__ float bf2f(ushort s) {
    return __uint_as_float(((unsigned)s) << 16);
}

// ---------------------------------------------------------------------------
// Kernel 1: batched gram partials.  grid = (nch, BATCH), 256 threads (4 waves).
// Each block: K-chunk of KC columns; G_partial = X_chunk @ X_chunk^T (128x128)
// via bf16 MFMA 16x16x32; also fp32 row sums of its chunk (register-accumulated,
// flushed once via LDS atomics after the K-loop).
// LDS stage layout: [(kb*4+kg)][row ^ (kg<<1)][e] bf16  (write & read 2-way max)
// ---------------------------------------------------------------------------
__global__ __launch_bounds__(256) void k_gram(const float* __restrict__ x,
                                              float* __restrict__ pG,
                                              float* __restrict__ pR,
                                              int nch, int KC) {
    __shared__ __align__(16) ushort st[8192];   // 2 kb * 4 kg * 128 rows * 8 e
    __shared__ float rsum[128];
    const int t    = threadIdx.x;
    const int lane = t & 63, wv = t >> 6;
    const int lr   = lane & 15, lk = lane >> 4;
    const int chunk = blockIdx.x, b = blockIdx.y;
    const size_t kbase = (size_t)chunk * KC;

    if (t < 128) rsum[t] = 0.f;

    float rs[8];
#pragma unroll
    for (int p = 0; p < 8; ++p) rs[p] = 0.f;

    f32x4 acc[2][8];
#pragma unroll
    for (int i = 0; i < 2; ++i)
#pragma unroll
        for (int j = 0; j < 8; ++j) acc[i][j] = (f32x4){0.f, 0.f, 0.f, 0.f};

    for (int k0 = 0; k0 < KC; k0 += 64) {
        float4 v[8];
#pragma unroll
        for (int p = 0; p < 8; ++p) {
            const int f4 = t + p * 256;
            const int row = f4 >> 4, kk = (f4 & 15) << 2;
            v[p] = *(const float4*)(x + ((size_t)(b * CHN + row)) * MLEN + kbase + k0 + kk);
        }
        __syncthreads();   // previous iter's LDS reads complete
#pragma unroll
        for (int p = 0; p < 8; ++p) {
            const int f4 = t + p * 256;
            const int row = f4 >> 4, kk = (f4 & 15) << 2;
            const int kb = kk >> 5, kg = (kk >> 3) & 3, e = kk & 7;
            ushort4 w;
            w.x = f2bf(v[p].x); w.y = f2bf(v[p].y); w.z = f2bf(v[p].z); w.w = f2bf(v[p].w);
            *(ushort4*)(&st[((kb * 4 + kg) * 128 + (row ^ (kg << 1))) * 8 + e]) = w;
            rs[p] += v[p].x + v[p].y + v[p].z + v[p].w;
        }
        __syncthreads();
#pragma unroll
        for (int kb = 0; kb < 2; ++kb) {
            bf16x8 fr[8];
#pragma unroll
            for (int f = 0; f < 8; ++f)
                fr[f] = *(const bf16x8*)(&st[((kb * 4 + lk) * 128 + ((f * 16 + lr) ^ (lk << 1))) * 8]);
#pragma unroll
            for (int rt = 0; rt < 2; ++rt)
#pragma unroll
                for (int ct = 0; ct < 8; ++ct)
                    acc[rt][ct] = __builtin_amdgcn_mfma_f32_16x16x32_bf16(
                        fr[2 * wv + rt], fr[ct], acc[rt][ct], 0, 0, 0);
        }
    }
    // flush row-sum partials (row for slot p is (t>>4) + 16p)
#pragma unroll
    for (int p = 0; p < 8; ++p) atomicAdd(&rsum[(t >> 4) + 16 * p], rs[p]);
    __syncthreads();
    float* G = pG + ((size_t)(b * nch + chunk)) * 16384;
#pragma unroll
    for (int rt = 0; rt < 2; ++rt)
#pragma unroll
        for (int ct = 0; ct < 8; ++ct)
#pragma unroll
            for (int r = 0; r < 4; ++r) {
                const int row = wv * 32 + rt * 16 + lk * 4 + r;   // C/D: row=(l>>4)*4+reg
                const int col = ct * 16 + lr;                     //      col=l&15
                G[row * 128 + col] = acc[rt][ct][r];
            }
    if (t < 128) pR[((size_t)(b * nch + chunk)) * 128 + t] = rsum[t];
}

// ---------------------------------------------------------------------------
// Kernel 2: reduce partials -> cov, accumulate normA.  grid=(16 slices, BATCH).
// cov[i][j] = (G[i][j] - r_i*r_j/M)/M ;  normA[b] += partial sums (atomic).
// ---------------------------------------------------------------------------
__global__ __launch_bounds__(256) void k_cov(const float* __restrict__ pG,
                                             const float* __restrict__ pR,
                                             int nch,
                                             float* __restrict__ cov,
                                             float* __restrict__ nA) {
    __shared__ float rs[128];
    __shared__ float red[4];
    const int t = threadIdx.x;
    const int s = blockIdx.x, b = blockIdx.y;
    if (t < 128) {
        float r = 0.f;
        for (int c = 0; c < nch; ++c) r += pR[((size_t)(b * nch + c)) * 128 + t];
        rs[t] = r;
    }
    __syncthreads();
    const float inv = 1.0f / (float)MLEN;
    const int idx4 = s * 256 + t;        // float4 index within 128x128
    const int i  = idx4 >> 5;
    const int j0 = (idx4 & 31) << 2;
    float4 g = {0.f, 0.f, 0.f, 0.f};
    for (int c = 0; c < nch; ++c) {
        const float4 pv = *(const float4*)(pG + ((size_t)(b * nch + c)) * 16384 + (size_t)idx4 * 4);
        g.x += pv.x; g.y += pv.y; g.z += pv.z; g.w += pv.w;
    }
    const float ri = rs[i] * inv;
    float4 cv;
    cv.x = (g.x - ri * rs[j0 + 0]) * inv;
    cv.y = (g.y - ri * rs[j0 + 1]) * inv;
    cv.z = (g.z - ri * rs[j0 + 2]) * inv;
    cv.w = (g.w - ri * rs[j0 + 3]) * inv;
    *(float4*)(cov + (size_t)b * 16384 + (size_t)idx4 * 4) = cv;
    float lsum = cv.x + cv.y + cv.z + cv.w;
#pragma unroll
    for (int off = 32; off; off >>= 1) lsum += __shfl_xor(lsum, off);
    if ((t & 63) == 0) red[t >> 6] = lsum;
    __syncthreads();
    if (t == 0) atomicAdd(nA + b, red[0] + red[1] + red[2] + red[3]);
}

// ---------------------------------------------------------------------------
// Kernel 3: Newton-Schulz in LDS (bf16, MFMA) + column-mean + FC -> gate.
// One block per batch, 4 waves. 3 x 32KB bf16 buffers, XOR-swizzled:
//   storage index = row*128 + (col ^ ((row&7)<<3))   (kills 256B-stride conflicts)
// All NS iterates are (near-)symmetric -> B-operand read row-major by symmetry.
// ---------------------------------------------------------------------------
__device__ __forceinline__ void zero_acc(f32x4 acc[2][8]) {
#pragma unroll
    for (int i = 0; i < 2; ++i)
#pragma unroll
        for (int j = 0; j < 8; ++j) acc[i][j] = (f32x4){0.f, 0.f, 0.f, 0.f};
}

__device__ __forceinline__ void ns_transform(const ushort* __restrict__ Z,
                                             ushort* __restrict__ W, int t) {
    // W = 0.5*(3I - Z)
#pragma unroll 4
    for (int p = 0; p < 64; ++p) {
        const int idx = t + p * 256;
        const int row = idx >> 7, cs = idx & 127;
        const int col = cs ^ ((row & 7) << 3);
        const float w = (row == col ? 1.5f : 0.0f) - 0.5f * bf2f(Z[idx]);
        W[idx] = f2bf(w);
    }
}

__device__ __forceinline__ void ns_mm(const ushort* __restrict__ L,
                                      const ushort* __restrict__ R,
                                      f32x4 acc[2][8], int wv, int lr, int lk) {
#pragma unroll
    for (int kb = 0; kb < 4; ++kb) {
        const int kof = kb * 32 + lk * 8;
        bf16x8 af[2], bfr[8];
#pragma unroll
        for (int rt = 0; rt < 2; ++rt) {
            const int row = wv * 32 + rt * 16 + lr;
            af[rt] = *(const bf16x8*)(L + row * 128 + (kof ^ ((row & 7) << 3)));
        }
#pragma unroll
        for (int ct = 0; ct < 8; ++ct) {
            const int row = ct * 16 + lr;     // B[k][n] = R[n][k] (symmetry)
            bfr[ct] = *(const bf16x8*)(R + row * 128 + (kof ^ ((row & 7) << 3)));
        }
#pragma unroll
        for (int rt = 0; rt < 2; ++rt)
#pragma unroll
            for (int ct = 0; ct < 8; ++ct)
                acc[rt][ct] = __builtin_amdgcn_mfma_f32_16x16x32_bf16(
                    af[rt], bfr[ct], acc[rt][ct], 0, 0, 0);
    }
}

__device__ __forceinline__ void ns_store(ushort* __restrict__ D,
                                         const f32x4 acc[2][8], int wv, int lr, int lk) {
#pragma unroll
    for (int rt = 0; rt < 2; ++rt)
#pragma unroll
        for (int ct = 0; ct < 8; ++ct)
#pragma unroll
            for (int r = 0; r < 4; ++r) {
                const int row = wv * 32 + rt * 16 + lk * 4 + r;
                const int col = ct * 16 + lr;
                D[row * 128 + (col ^ ((row & 7) << 3))] = f2bf(acc[rt][ct][r]);
            }
}

__global__ __launch_bounds__(256) void k_ns(const float* __restrict__ cov,
                                            const float* __restrict__ nA,
                                            const float* __restrict__ w1,
                                            const float* __restrict__ b1v,
                                            const float* __restrict__ w2,
                                            const float* __restrict__ b2v,
                                            float* __restrict__ gate) {
    __shared__ __align__(16) ushort buf[3][16384];
    __shared__ float scol[128];
    __shared__ float sef[128];
    __shared__ float hdn[16];
    const int t = threadIdx.x;
    const int lane = t & 63, wv = t >> 6;
    const int lr = lane & 15, lk = lane >> 4;
    const int b = blockIdx.x;
    const float invn = 1.0f / nA[b];

    // load A = cov/normA as bf16 (swizzled) into buf0
    for (int p = 0; p < 64; ++p) {
        const int idx = t + p * 256;
        const int i = idx >> 7, j = idx & 127;
        buf[0][i * 128 + (j ^ ((i & 7) << 3))] = f2bf(cov[(size_t)b * 16384 + idx] * invn);
    }
    __syncthreads();

    f32x4 acc[2][8];

    // ZY0 = 0.5*(3I - A) -> buf1 ; this is also Z1
    ns_transform(buf[0], buf[1], t);
    __syncthreads();
    // Y1 = A @ ZY0 -> buf2
    zero_acc(acc); ns_mm(buf[0], buf[1], acc, wv, lr, lk);
    __syncthreads(); ns_store(buf[2], acc, wv, lr, lk); __syncthreads();

    // 3 middle iterations:  Y=buf2, Z=buf1, scratch=buf0
    for (int it = 0; it < 3; ++it) {
        ns_transform(buf[1], buf[0], t);              // W = 0.5*(3I - Z)
        __syncthreads();
        zero_acc(acc); ns_mm(buf[0], buf[2], acc, wv, lr, lk);   // ZY = W @ Y
        __syncthreads(); ns_store(buf[0], acc, wv, lr, lk); __syncthreads();
        zero_acc(acc); ns_mm(buf[2], buf[0], acc, wv, lr, lk);   // Ynew = Y @ ZY
        __syncthreads(); ns_store(buf[2], acc, wv, lr, lk); __syncthreads();
        zero_acc(acc); ns_mm(buf[0], buf[1], acc, wv, lr, lk);   // Znew = ZY @ Z
        __syncthreads(); ns_store(buf[1], acc, wv, lr, lk); __syncthreads();
    }

    // final: ZYf = (Y @ 0.5*(3I - Z)) @ Y
    ns_transform(buf[1], buf[0], t);                  // W2
    __syncthreads();
    zero_acc(acc); ns_mm(buf[2], buf[0], acc, wv, lr, lk);       // T = Y @ W2
    __syncthreads(); ns_store(buf[1], acc, wv, lr, lk); __syncthreads();
    zero_acc(acc); ns_mm(buf[1], buf[2], acc, wv, lr, lk);       // ZYf = T @ Y (in regs)

    // column sums of ZYf  (s = colmean * sqrt(normA))
    if (t < 128) scol[t] = 0.f;
    __syncthreads();
#pragma unroll
    for (int ct = 0; ct < 8; ++ct) {
        float s = 0.f;
#pragma unroll
        for (int rt = 0; rt < 2; ++rt)
#pragma unroll
            for (int r = 0; r < 4; ++r) s += acc[rt][ct][r];
        atomicAdd(&scol[ct * 16 + lr], s);
    }
    __syncthreads();
    const float sc = sqrtf(nA[b]) * (1.0f / 128.0f);
    if (t < 128) sef[t] = scol[t] * sc;
    __syncthreads();
    if (t < 16) {
        float a = b1v[t];
        for (int c = 0; c < 128; ++c) a += sef[c] * w1[t * 128 + c];
        hdn[t] = fmaxf(a, 0.f);
    }
    __syncthreads();
    if (t < 128) {
        float a = b2v[t];
#pragma unroll
        for (int j = 0; j < 16; ++j) a += hdn[j] * w2[t * 16 + j];
        gate[b * 128 + t] = 1.0f / (1.0f + expf(-a));
    }
}

// ---------------------------------------------------------------------------
// Kernel 4: out = gate[b,c] * x   (float4 streaming)
// ---------------------------------------------------------------------------
__global__ __launch_bounds__(256) void k_scale(const float4* __restrict__ x4,
                                               const float* __restrict__ gate,
                                               float4* __restrict__ o4) {
    const int total = BATCH * CHN * (MLEN / 4);
    for (int i = blockIdx.x * 256 + threadIdx.x; i < total; i += gridDim.x * 256) {
        const int bc = i / (MLEN / 4);
        const float g = gate[bc];
        const float4 v = x4[i];
        float4 o;
        o.x = v.x * g; o.y = v.y * g; o.z = v.z * g; o.w = v.w * g;
        o4[i] = o;
    }
}

// ---------------------------------------------------------------------------
extern "C" void kernel_launch(void* const* d_in, const int* in_sizes, int n_in,
                              void* d_out, int out_size, void* d_ws, size_t ws_size,
                              hipStream_t stream) {
    const float* x  = (const float*)d_in[0];
    const float* w1 = (const float*)d_in[1];
    const float* b1 = (const float*)d_in[2];
    const float* w2 = (const float*)d_in[3];
    const float* b2 = (const float*)d_in[4];
    float* out = (float*)d_out;

    int nch = 32;   // K-chunks per batch (grid = nch*16 blocks for k_gram)
    auto need = [](int n) -> size_t {
        return (size_t)n * BATCH * 16384 * 4     // partial grams
             + (size_t)n * BATCH * 128 * 4       // partial rowsums
             + (size_t)BATCH * 16384 * 4         // cov
             + 256                               // normA
             + (size_t)BATCH * CHN * 4;          // gate
    };
    while (nch > 2 && need(nch) > ws_size) nch >>= 1;
    const int KC = MLEN / nch;                   // multiple of 64 for nch in {2..32}

    char* p = (char*)d_ws;
    float* pG   = (float*)p; p += (size_t)nch * BATCH * 16384 * 4;
    float* pR   = (float*)p; p += (size_t)nch * BATCH * 128 * 4;
    float* cov  = (float*)p; p += (size_t)BATCH * 16384 * 4;
    float* nA   = (float*)p; p += 256;
    float* gate = (float*)p;

    hipMemsetAsync(nA, 0, BATCH * sizeof(float), stream);
    k_gram<<<dim3(nch, BATCH), 256, 0, stream>>>(x, pG, pR, nch, KC);
    k_cov<<<dim3(16, BATCH), 256, 0, stream>>>(pG, pR, nch, cov, nA);
    k_ns<<<BATCH, 256, 0, stream>>>(cov, nA, w1, b1, w2, b2, gate);
    k_scale<<<4096, 256, 0, stream>>>((const float4*)x, gate, (float4*)out);
}

// Round 3
// 615.085 us; speedup vs baseline: 1.3293x; 1.3293x over previous
//
#include <hip/hip_runtime.h>
#include <hip/hip_bf16.h>

// SOCA forward: cov-pool -> Newton-Schulz sqrtm (5 iters) -> SE gate -> scale.
// B=16, C=128, H=W=192, M=36864, RED=8 (cr=16).

#define BATCH 16
#define CHN   128
#define MLEN  36864
#define NCH   32            // K-chunks per batch (confirmed fits ws in round 2)
#define KC    (MLEN / NCH)  // 1152
#define NITER (KC / 64)     // 18

typedef short bf16x8 __attribute__((ext_vector_type(8)));
typedef float f32x4  __attribute__((ext_vector_type(4)));

__device__ __forceinline__ ushort f2bf(float f) {
    unsigned u = __float_as_uint(f);
    u = (u + 0x7FFFu + ((u >> 16) & 1u)) >> 16;   // RNE
    return (ushort)u;
}
__device__ __forceinline__ float bf2f(ushort s) {
    return __uint_as_float(((unsigned)s) << 16);
}

// ---------------------------------------------------------------------------
// Kernel 1: batched gram partials.  grid = (NCH, BATCH), 256 threads (4 waves).
// G_partial = X_chunk @ X_chunk^T (128x128) via bf16 MFMA 16x16x32 + fp32 row
// sums. Software-pipelined: next tile's global loads issue before the MFMA
// section. MFMA fragments are constant-indexed (rule #20: no runtime-indexed
// ext_vector arrays — wv folded into the LDS address instead).
// LDS layout: [(kb*4+kg)][row ^ (kg<<1)][e] bf16.
// ---------------------------------------------------------------------------
__global__ __launch_bounds__(256) void k_gram(const float* __restrict__ x,
                                              float* __restrict__ pG,
                                              float* __restrict__ pR) {
    __shared__ __align__(16) ushort st[8192];   // 2 kb * 4 kg * 128 rows * 8 e
    __shared__ float rsum[128];
    const int t    = threadIdx.x;
    const int lane = t & 63, wv = t >> 6;
    const int lr   = lane & 15, lk = lane >> 4;
    const int chunk = blockIdx.x, b = blockIdx.y;

    if (t < 128) rsum[t] = 0.f;

    // per-thread invariants: kk (col offset in 64-tile) fixed, rows r0+16p
    const int r0  = t >> 4;
    const int kk  = (t & 15) << 2;
    const int kb0 = kk >> 5, kg0 = (kk >> 3) & 3, e0 = kk & 7;
    ushort* stw = &st[((kb0 * 4 + kg0) * 128) * 8 + e0];
    const float* xbase = x + (size_t)(b * CHN) * MLEN + (size_t)chunk * KC + kk;

    float rs[8];
#pragma unroll
    for (int p = 0; p < 8; ++p) rs[p] = 0.f;
    f32x4 acc[2][8];
#pragma unroll
    for (int i = 0; i < 2; ++i)
#pragma unroll
        for (int j = 0; j < 8; ++j) acc[i][j] = (f32x4){0.f, 0.f, 0.f, 0.f};

#define LOADV(V, IT)                                                          \
    _Pragma("unroll") for (int p = 0; p < 8; ++p)                             \
        V[p] = *(const float4*)(xbase + (size_t)(r0 + 16 * p) * MLEN + (IT) * 64);

#define STAGEV(V)                                                             \
    _Pragma("unroll") for (int p = 0; p < 8; ++p) {                           \
        union { ushort4 u; __hip_bfloat162 h[2]; } cv;                        \
        cv.h[0] = __float22bfloat162_rn(make_float2(V[p].x, V[p].y));         \
        cv.h[1] = __float22bfloat162_rn(make_float2(V[p].z, V[p].w));         \
        *(ushort4*)(stw + ((r0 + 16 * p) ^ (kg0 << 1)) * 8) = cv.u;           \
        rs[p] += (V[p].x + V[p].y) + (V[p].z + V[p].w);                       \
    }

#define MFMAS()                                                               \
    _Pragma("unroll") for (int kb = 0; kb < 2; ++kb) {                        \
        const int sb = (kb * 4 + lk) * 128;                                   \
        bf16x8 af[2], bfr[8];                                                 \
        _Pragma("unroll") for (int rt = 0; rt < 2; ++rt)                      \
            af[rt] = *(const bf16x8*)&st[(sb + ((wv * 32 + rt * 16 + lr) ^ (lk << 1))) * 8]; \
        _Pragma("unroll") for (int ct = 0; ct < 8; ++ct)                      \
            bfr[ct] = *(const bf16x8*)&st[(sb + ((ct * 16 + lr) ^ (lk << 1))) * 8]; \
        _Pragma("unroll") for (int rt = 0; rt < 2; ++rt)                      \
            _Pragma("unroll") for (int ct = 0; ct < 8; ++ct)                  \
                acc[rt][ct] = __builtin_amdgcn_mfma_f32_16x16x32_bf16(        \
                    af[rt], bfr[ct], acc[rt][ct], 0, 0, 0);                   \
    }

    float4 vA[8], vB[8];
    LOADV(vA, 0);
    int it = 0;
    while (true) {
        __syncthreads();                 // prev MFMA reads done; loads drained
        STAGEV(vA);
        __syncthreads();
        if (it + 1 < NITER) LOADV(vB, it + 1);   // prefetch overlaps MFMA
        MFMAS();
        if (++it >= NITER) break;
        __syncthreads();
        STAGEV(vB);
        __syncthreads();
        if (it + 1 < NITER) LOADV(vA, it + 1);
        MFMAS();
        if (++it >= NITER) break;
    }

    // flush row-sum partials (row for slot p is r0 + 16p)
#pragma unroll
    for (int p = 0; p < 8; ++p) atomicAdd(&rsum[r0 + 16 * p], rs[p]);
    __syncthreads();
    float* G = pG + ((size_t)(b * NCH + chunk)) * 16384;
#pragma unroll
    for (int rt = 0; rt < 2; ++rt)
#pragma unroll
        for (int ct = 0; ct < 8; ++ct)
#pragma unroll
            for (int r = 0; r < 4; ++r) {
                const int row = wv * 32 + rt * 16 + lk * 4 + r;  // C/D: row=(l>>4)*4+reg
                const int col = ct * 16 + lr;                    //      col=l&15
                G[row * 128 + col] = acc[rt][ct][r];
            }
    if (t < 128) pR[((size_t)(b * NCH + chunk)) * 128 + t] = rsum[t];
}

// ---------------------------------------------------------------------------
// Kernel 2: reduce partials -> cov, accumulate normA.  grid=(16 slices, BATCH).
// cov[i][j] = (G[i][j] - r_i*r_j/M)/M ;  normA[b] += partial sums (atomic).
// ---------------------------------------------------------------------------
__global__ __launch_bounds__(256) void k_cov(const float* __restrict__ pG,
                                             const float* __restrict__ pR,
                                             float* __restrict__ cov,
                                             float* __restrict__ nA) {
    __shared__ float rs[128];
    __shared__ float red[4];
    const int t = threadIdx.x;
    const int s = blockIdx.x, b = blockIdx.y;
    if (t < 128) {
        float r = 0.f;
        for (int c = 0; c < NCH; ++c) r += pR[((size_t)(b * NCH + c)) * 128 + t];
        rs[t] = r;
    }
    __syncthreads();
    const float inv = 1.0f / (float)MLEN;
    const int idx4 = s * 256 + t;        // float4 index within 128x128
    const int i  = idx4 >> 5;
    const int j0 = (idx4 & 31) << 2;
    float4 g = {0.f, 0.f, 0.f, 0.f};
    for (int c = 0; c < NCH; ++c) {
        const float4 pv = *(const float4*)(pG + ((size_t)(b * NCH + c)) * 16384 + (size_t)idx4 * 4);
        g.x += pv.x; g.y += pv.y; g.z += pv.z; g.w += pv.w;
    }
    const float ri = rs[i] * inv;
    float4 cv;
    cv.x = (g.x - ri * rs[j0 + 0]) * inv;
    cv.y = (g.y - ri * rs[j0 + 1]) * inv;
    cv.z = (g.z - ri * rs[j0 + 2]) * inv;
    cv.w = (g.w - ri * rs[j0 + 3]) * inv;
    *(float4*)(cov + (size_t)b * 16384 + (size_t)idx4 * 4) = cv;
    float lsum = cv.x + cv.y + cv.z + cv.w;
#pragma unroll
    for (int off = 32; off; off >>= 1) lsum += __shfl_xor(lsum, off);
    if ((t & 63) == 0) red[t >> 6] = lsum;
    __syncthreads();
    if (t == 0) atomicAdd(nA + b, red[0] + red[1] + red[2] + red[3]);
}

// ---------------------------------------------------------------------------
// Kernel 3: Newton-Schulz in LDS (bf16, MFMA) + column-mean + FC -> gate.
// One block per batch, 4 waves, 4 x 32KB XOR-swizzled bf16 buffers:
//   storage index = row*128 + (col ^ ((row&7)<<3))
// Transform fusion: ZY = 0.5*(3I - Z) @ Y is computed as 1.5*Y - 0.5*(Z@Y),
// folded into the product's store — no separate LDS transform passes.
// All iterates are polynomials in A -> symmetric & commuting, so the MFMA
// B-operand reads R row-major via symmetry.
// ---------------------------------------------------------------------------
__device__ __forceinline__ void zero_acc(f32x4 acc[2][8]) {
#pragma unroll
    for (int i = 0; i < 2; ++i)
#pragma unroll
        for (int j = 0; j < 8; ++j) acc[i][j] = (f32x4){0.f, 0.f, 0.f, 0.f};
}

__device__ __forceinline__ void ns_mm(const ushort* __restrict__ L,
                                      const ushort* __restrict__ R,
                                      f32x4 acc[2][8], int wv, int lr, int lk) {
#pragma unroll
    for (int kb = 0; kb < 4; ++kb) {
        const int kof = kb * 32 + lk * 8;
        bf16x8 af[2], bfr[8];
#pragma unroll
        for (int rt = 0; rt < 2; ++rt) {
            const int row = wv * 32 + rt * 16 + lr;
            af[rt] = *(const bf16x8*)(L + row * 128 + (kof ^ ((row & 7) << 3)));
        }
#pragma unroll
        for (int ct = 0; ct < 8; ++ct) {
            const int row = ct * 16 + lr;     // B[k][n] = R[n][k] (symmetry)
            bfr[ct] = *(const bf16x8*)(R + row * 128 + (kof ^ ((row & 7) << 3)));
        }
#pragma unroll
        for (int rt = 0; rt < 2; ++rt)
#pragma unroll
            for (int ct = 0; ct < 8; ++ct)
                acc[rt][ct] = __builtin_amdgcn_mfma_f32_16x16x32_bf16(
                    af[rt], bfr[ct], acc[rt][ct], 0, 0, 0);
    }
}

// plain store: D = acc
__device__ __forceinline__ void ns_store(ushort* __restrict__ D,
                                         const f32x4 acc[2][8], int wv, int lr, int lk) {
#pragma unroll
    for (int rt = 0; rt < 2; ++rt)
#pragma unroll
        for (int ct = 0; ct < 8; ++ct)
#pragma unroll
            for (int r = 0; r < 4; ++r) {
                const int row = wv * 32 + rt * 16 + lk * 4 + r;
                const int col = ct * 16 + lr;
                D[row * 128 + (col ^ ((row & 7) << 3))] = f2bf(acc[rt][ct][r]);
            }
}

// fused transform store: D = 1.5*Ysrc - 0.5*acc   (D != Ysrc)
__device__ __forceinline__ void ns_store_t(ushort* __restrict__ D,
                                           const ushort* __restrict__ Ysrc,
                                           const f32x4 acc[2][8], int wv, int lr, int lk) {
#pragma unroll
    for (int rt = 0; rt < 2; ++rt)
#pragma unroll
        for (int ct = 0; ct < 8; ++ct)
#pragma unroll
            for (int r = 0; r < 4; ++r) {
                const int row = wv * 32 + rt * 16 + lk * 4 + r;
                const int col = ct * 16 + lr;
                const int si  = row * 128 + (col ^ ((row & 7) << 3));
                D[si] = f2bf(1.5f * bf2f(Ysrc[si]) - 0.5f * acc[rt][ct][r]);
            }
}

__global__ __launch_bounds__(256) void k_ns(const float* __restrict__ cov,
                                            const float* __restrict__ nA,
                                            const float* __restrict__ w1,
                                            const float* __restrict__ b1v,
                                            const float* __restrict__ w2,
                                            const float* __restrict__ b2v,
                                            float* __restrict__ gate) {
    __shared__ __align__(16) ushort bufs[4][16384];
    __shared__ float scol[128];
    __shared__ float sef[128];
    __shared__ float hdn[16];
    const int t = threadIdx.x;
    const int lane = t & 63, wv = t >> 6;
    const int lr = lane & 15, lk = lane >> 4;
    const int b = blockIdx.x;
    const float invn = 1.0f / nA[b];
    ushort* base = &bufs[0][0];

    // buf0 = A = cov/normA ; buf1 = Z1 = ZY0 = 1.5I - 0.5A   (both swizzled)
    for (int p = 0; p < 64; ++p) {
        const int idx = t + p * 256;
        const int i = idx >> 7, j = idx & 127;
        const float a = cov[(size_t)b * 16384 + idx] * invn;
        const int si = i * 128 + (j ^ ((i & 7) << 3));
        base[si]         = f2bf(a);
        base[16384 + si] = f2bf((i == j ? 1.5f : 0.f) - 0.5f * a);
    }
    __syncthreads();

    f32x4 acc[2][8];

    // Y1 = A @ ZY0 = 1.5A - 0.5*(A@A)  -> buf2
    zero_acc(acc);
    ns_mm(base, base, acc, wv, lr, lk);
    ns_store_t(base + 2 * 16384, base, acc, wv, lr, lk);
    __syncthreads();

    int y = 2, z = 1, f1 = 0, f2 = 3;
    for (int itn = 0; itn < 3; ++itn) {
        ushort* Y = base + y * 16384;
        ushort* Z = base + z * 16384;
        ushort* T = base + f1 * 16384;
        ushort* N = base + f2 * 16384;
        // T = ZY = 1.5Y - 0.5*(Z@Y)
        zero_acc(acc); ns_mm(Z, Y, acc, wv, lr, lk);
        ns_store_t(T, Y, acc, wv, lr, lk);
        __syncthreads();
        // Ynew = Y @ T -> N
        zero_acc(acc); ns_mm(Y, T, acc, wv, lr, lk);
        ns_store(N, acc, wv, lr, lk);
        // Znew = T @ Z   (store into old-Y slot after barrier)
        zero_acc(acc); ns_mm(T, Z, acc, wv, lr, lk);
        __syncthreads();               // all waves past Y-reads; N visible
        ns_store(Y, acc, wv, lr, lk);
        __syncthreads();
        const int oy = y, oz = z, of1 = f1, of2 = f2;
        y = of2; z = oy; f1 = oz; f2 = of1;
    }

    // final: ZYf = (1.5Y - 0.5*(Y@Z)) @ Y   (first factor -> f1, result in regs)
    {
        ushort* Y = base + y * 16384;
        ushort* Z = base + z * 16384;
        ushort* T = base + f1 * 16384;
        zero_acc(acc); ns_mm(Y, Z, acc, wv, lr, lk);
        ns_store_t(T, Y, acc, wv, lr, lk);
        __syncthreads();
        zero_acc(acc); ns_mm(T, Y, acc, wv, lr, lk);   // ZYf in regs
    }

    // column sums of ZYf  (s = colmean * sqrt(normA))
    if (t < 128) scol[t] = 0.f;
    __syncthreads();
#pragma unroll
    for (int ct = 0; ct < 8; ++ct) {
        float s = 0.f;
#pragma unroll
        for (int rt = 0; rt < 2; ++rt)
#pragma unroll
            for (int r = 0; r < 4; ++r) s += acc[rt][ct][r];
        atomicAdd(&scol[ct * 16 + lr], s);
    }
    __syncthreads();
    const float sc = sqrtf(nA[b]) * (1.0f / 128.0f);
    if (t < 128) sef[t] = scol[t] * sc;
    __syncthreads();
    if (t < 16) {
        float a = b1v[t];
        for (int c = 0; c < 128; ++c) a += sef[c] * w1[t * 128 + c];
        hdn[t] = fmaxf(a, 0.f);
    }
    __syncthreads();
    if (t < 128) {
        float a = b2v[t];
#pragma unroll
        for (int j = 0; j < 16; ++j) a += hdn[j] * w2[t * 16 + j];
        gate[b * 128 + t] = 1.0f / (1.0f + expf(-a));
    }
}

// ---------------------------------------------------------------------------
// Kernel 4: out = gate[b,c] * x.  grid = (3, B*C): no integer division.
// Each block: 256 threads x 12 float4 of one (b,c) row.  3*256*12 = 9216.
// ---------------------------------------------------------------------------
__global__ __launch_bounds__(256) void k_scale(const float4* __restrict__ x4,
                                               const float* __restrict__ gate,
                                               float4* __restrict__ o4) {
    const int bc = blockIdx.y;
    const float g = gate[bc];
    const int basei = bc * (MLEN / 4) + blockIdx.x * 3072 + threadIdx.x;
#pragma unroll
    for (int j = 0; j < 12; ++j) {
        const float4 v = x4[basei + j * 256];
        float4 o;
        o.x = v.x * g; o.y = v.y * g; o.z = v.z * g; o.w = v.w * g;
        o4[basei + j * 256] = o;
    }
}

// ---------------------------------------------------------------------------
extern "C" void kernel_launch(void* const* d_in, const int* in_sizes, int n_in,
                              void* d_out, int out_size, void* d_ws, size_t ws_size,
                              hipStream_t stream) {
    const float* x  = (const float*)d_in[0];
    const float* w1 = (const float*)d_in[1];
    const float* b1 = (const float*)d_in[2];
    const float* w2 = (const float*)d_in[3];
    const float* b2 = (const float*)d_in[4];
    float* out = (float*)d_out;

    char* p = (char*)d_ws;
    float* pG   = (float*)p; p += (size_t)NCH * BATCH * 16384 * 4;
    float* pR   = (float*)p; p += (size_t)NCH * BATCH * 128 * 4;
    float* cov  = (float*)p; p += (size_t)BATCH * 16384 * 4;
    float* nA   = (float*)p; p += 256;
    float* gate = (float*)p;

    hipMemsetAsync(nA, 0, BATCH * sizeof(float), stream);
    k_gram<<<dim3(NCH, BATCH), 256, 0, stream>>>(x, pG, pR);
    k_cov<<<dim3(16, BATCH), 256, 0, stream>>>(pG, pR, cov, nA);
    k_ns<<<BATCH, 256, 0, stream>>>(cov, nA, w1, b1, w2, b2, gate);
    k_scale<<<dim3(3, BATCH * CHN), 256, 0, stream>>>((const float4*)x, gate, (float4*)out);
}

// Round 5
// 587.939 us; speedup vs baseline: 1.3907x; 1.0462x over previous
//
#include <hip/hip_runtime.h>
#include <hip/hip_bf16.h>

// SOCA forward: cov-pool -> Newton-Schulz sqrtm (5 iters) -> SE gate -> scale.
// B=16, C=128, H=W=192, M=36864, RED=8 (cr=16).

#define BATCH 16
#define CHN   128
#define MLEN  36864
#define NCH   64             // K-chunks per batch
#define KC    (MLEN / NCH)   // 576
#define KSTEP 32
#define NITER (KC / KSTEP)   // 18

typedef short  bf16x8 __attribute__((ext_vector_type(8)));
typedef float  f32x4  __attribute__((ext_vector_type(4)));
typedef ushort u16x4  __attribute__((ext_vector_type(4)));
typedef float  f4     __attribute__((ext_vector_type(4)));

__device__ __forceinline__ ushort f2bf(float f) {
    unsigned u = __float_as_uint(f);
    u = (u + 0x7FFFu + ((u >> 16) & 1u)) >> 16;   // RNE
    return (ushort)u;
}
__device__ __forceinline__ float bf2f(ushort s) {
    return __uint_as_float(((unsigned)s) << 16);
}
__device__ __forceinline__ bf16x8 pack8(f32x4 a, f32x4 b) {
    union { bf16x8 v; __hip_bfloat162 h[4]; } u;
    u.h[0] = __float22bfloat162_rn(make_float2(a[0], a[1]));
    u.h[1] = __float22bfloat162_rn(make_float2(a[2], a[3]));
    u.h[2] = __float22bfloat162_rn(make_float2(b[0], b[1]));
    u.h[3] = __float22bfloat162_rn(make_float2(b[2], b[3]));
    return u.v;
}

// ---------------------------------------------------------------------------
// Kernel 1: batched gram partials, m97 structure.  grid=(NCH, BATCH), 256 thr.
// fp32 x staged via global_load_lds (16B) into 2x16KB LDS dbuf, ONE barrier
// per K-step; bf16 conversion happens on LDS->reg fragment read (cvt_pk).
// LDS layout: [row][quad kq_s] with kq_s = kq_g ^ (row&6)  (pair-preserving
// XOR swizzle -> <=4-way ds_read conflicts; global source pre-swizzled).
// Row sums via MFMA against a ones-fragment (consistent with bf16-x gram).
// Partial G written in bf16, MFMA-layout order (coalesced 8B stores).
// ---------------------------------------------------------------------------
__global__ __launch_bounds__(256, 4) void k_gram(const float* __restrict__ x,
                                                 ushort* __restrict__ pG,
                                                 float* __restrict__ pR) {
    __shared__ __align__(16) float xs[2][128 * KSTEP];   // 2 x 16 KB
    const int t    = threadIdx.x;
    const int lane = t & 63, wv = t >> 6;
    const int lr   = lane & 15, lk = lane >> 4;
    const int chunk = blockIdx.x, b = blockIdx.y;

    // per-lane global source for global_load_lds: instruction j covers LDS
    // rows 8*(wv*4+j)..+7; lane -> row_local = lane>>3, kq_s = lane&7,
    // global quad kq_g = kq_s ^ (row&6) = (lane&7) ^ ((lane>>3)&6).
    const int grow = lane >> 3;
    const int kqg  = (lane & 7) ^ (grow & 6);
    const float* gsrc[4];
#pragma unroll
    for (int j = 0; j < 4; ++j) {
        const int row = (wv * 4 + j) * 8 + grow;
        gsrc[j] = x + (size_t)(b * CHN + row) * MLEN + (size_t)chunk * KC + kqg * 4;
    }

#define ISSUE(BUF, IT)                                                         \
    _Pragma("unroll") for (int j = 0; j < 4; ++j) {                            \
        __builtin_amdgcn_global_load_lds(                                      \
            (const __attribute__((address_space(1))) void*)(gsrc[j] + (IT) * KSTEP), \
            (__attribute__((address_space(3))) void*)&xs[BUF][(wv * 4 + j) * 256],   \
            16, 0, 0);                                                         \
    }

    bf16x8 bONE;
#pragma unroll
    for (int i = 0; i < 8; ++i) bONE[i] = (short)0x3F80;   // 1.0bf16

    f32x4 acc[2][8];
    f32x4 acc_r[2];
#pragma unroll
    for (int i = 0; i < 2; ++i) {
        acc_r[i] = (f32x4){0.f, 0.f, 0.f, 0.f};
#pragma unroll
        for (int j = 0; j < 8; ++j) acc[i][j] = (f32x4){0.f, 0.f, 0.f, 0.f};
    }

    ISSUE(0, 0);
    __syncthreads();
    for (int it = 0; it < NITER; ++it) {
        const int cur = it & 1;
        if (it + 1 < NITER) ISSUE(cur ^ 1, it + 1);
        {
            const float* S = xs[cur];
            bf16x8 af[2];
#pragma unroll
            for (int rt = 0; rt < 2; ++rt) {
                const int row = wv * 32 + rt * 16 + lr;
                const int q0  = (2 * lk) ^ (row & 6);
                const f32x4 a0 = *(const f32x4*)(S + row * KSTEP + q0 * 4);
                const f32x4 a1 = *(const f32x4*)(S + row * KSTEP + q0 * 4 + 4);
                af[rt] = pack8(a0, a1);
            }
            acc_r[0] = __builtin_amdgcn_mfma_f32_16x16x32_bf16(af[0], bONE, acc_r[0], 0, 0, 0);
            acc_r[1] = __builtin_amdgcn_mfma_f32_16x16x32_bf16(af[1], bONE, acc_r[1], 0, 0, 0);
#pragma unroll
            for (int ct = 0; ct < 8; ++ct) {
                const int row = ct * 16 + lr;
                const int q0  = (2 * lk) ^ (row & 6);
                const f32x4 b0 = *(const f32x4*)(S + row * KSTEP + q0 * 4);
                const f32x4 b1 = *(const f32x4*)(S + row * KSTEP + q0 * 4 + 4);
                const bf16x8 bfr = pack8(b0, b1);
                acc[0][ct] = __builtin_amdgcn_mfma_f32_16x16x32_bf16(af[0], bfr, acc[0][ct], 0, 0, 0);
                acc[1][ct] = __builtin_amdgcn_mfma_f32_16x16x32_bf16(af[1], bfr, acc[1][ct], 0, 0, 0);
            }
        }
        __syncthreads();   // drains next-tile loads; syncs LDS reads
    }

    // epilogue: bf16 partial-G in MFMA-layout order, coalesced 8B stores
    ushort* Gc = pG + ((size_t)(b * NCH + chunk)) * 16384;
#pragma unroll
    for (int rt = 0; rt < 2; ++rt)
#pragma unroll
        for (int ct = 0; ct < 8; ++ct) {
            union { u16x4 u; __hip_bfloat162 h[2]; } cv;
            cv.h[0] = __float22bfloat162_rn(make_float2(acc[rt][ct][0], acc[rt][ct][1]));
            cv.h[1] = __float22bfloat162_rn(make_float2(acc[rt][ct][2], acc[rt][ct][3]));
            *(u16x4*)(Gc + (((wv * 2 + rt) * 8 + ct) * 64 + lane) * 4) = cv.u;
        }
    if (lr == 0) {
        float* Rc = pR + ((size_t)(b * NCH + chunk)) * 128;
#pragma unroll
        for (int rt = 0; rt < 2; ++rt)
#pragma unroll
            for (int r = 0; r < 4; ++r)
                Rc[wv * 32 + rt * 16 + lk * 4 + r] = acc_r[rt][r];
    }
#undef ISSUE
}

// ---------------------------------------------------------------------------
// Kernel 2: reduce bf16 partials (MFMA-layout order) -> cov, normA partials.
// grid=(16, BATCH).  nA[b*16+s] written per-slot (no atomics, no memset).
// ---------------------------------------------------------------------------
__global__ __launch_bounds__(256) void k_cov(const ushort* __restrict__ pG,
                                             const float* __restrict__ pR,
                                             float* __restrict__ cov,
                                             float* __restrict__ nA) {
    __shared__ float rs[128];
    __shared__ float red[4];
    const int t = threadIdx.x;
    const int s = blockIdx.x, b = blockIdx.y;
    if (t < 128) {
        float r = 0.f;
        for (int c = 0; c < NCH; ++c) r += pR[((size_t)(b * NCH + c)) * 128 + t];
        rs[t] = r;
    }
    __syncthreads();
    const int qi = s * 256 + t;                 // ushort4 index in 16384-short tile
    const ushort* base = pG + (size_t)b * NCH * 16384 + (size_t)qi * 4;
    float g0 = 0.f, g1 = 0.f, g2 = 0.f, g3 = 0.f;
    for (int c = 0; c < NCH; ++c) {
        const u16x4 u = *(const u16x4*)(base + (size_t)c * 16384);
        g0 += bf2f(u[0]); g1 += bf2f(u[1]); g2 += bf2f(u[2]); g3 += bf2f(u[3]);
    }
    // decode MFMA-layout index -> (row, col)
    const int lane6 = qi & 63;
    const int ct  = (qi >> 6) & 7;
    const int rt  = (qi >> 9) & 1;
    const int wvq = (qi >> 10) & 3;
    const int row0 = wvq * 32 + rt * 16 + (lane6 >> 4) * 4;
    const int col  = ct * 16 + (lane6 & 15);
    const float inv = 1.0f / (float)MLEN;
    const float rc  = rs[col] * inv;
    float* cb = cov + (size_t)b * 16384 + col;
    const float cv0 = (g0 - rs[row0 + 0] * rc) * inv;
    const float cv1 = (g1 - rs[row0 + 1] * rc) * inv;
    const float cv2 = (g2 - rs[row0 + 2] * rc) * inv;
    const float cv3 = (g3 - rs[row0 + 3] * rc) * inv;
    cb[(row0 + 0) * 128] = cv0;
    cb[(row0 + 1) * 128] = cv1;
    cb[(row0 + 2) * 128] = cv2;
    cb[(row0 + 3) * 128] = cv3;
    float lsum = (cv0 + cv1) + (cv2 + cv3);
#pragma unroll
    for (int off = 32; off; off >>= 1) lsum += __shfl_xor(lsum, off);
    if ((t & 63) == 0) red[t >> 6] = lsum;
    __syncthreads();
    if (t == 0) nA[b * 16 + s] = (red[0] + red[1]) + (red[2] + red[3]);
}

// ---------------------------------------------------------------------------
// Kernel 3: Newton-Schulz in LDS (bf16, MFMA) + column-mean + FC -> gate.
// One block per batch, 4 waves, 4 x 32KB XOR-swizzled bf16 buffers:
//   storage index = row*128 + (col ^ ((row&7)<<3))
// Transform fusion: ZY = 0.5*(3I - Z) @ Y computed as 1.5*Y - 0.5*(Z@Y).
// Iterates are polynomials in A -> symmetric, so B-operand reads R row-major.
// ---------------------------------------------------------------------------
__device__ __forceinline__ void zero_acc(f32x4 acc[2][8]) {
#pragma unroll
    for (int i = 0; i < 2; ++i)
#pragma unroll
        for (int j = 0; j < 8; ++j) acc[i][j] = (f32x4){0.f, 0.f, 0.f, 0.f};
}

__device__ __forceinline__ void ns_mm(const ushort* __restrict__ L,
                                      const ushort* __restrict__ R,
                                      f32x4 acc[2][8], int wv, int lr, int lk) {
#pragma unroll
    for (int kb = 0; kb < 4; ++kb) {
        const int kof = kb * 32 + lk * 8;
        bf16x8 af[2], bfr[8];
#pragma unroll
        for (int rt = 0; rt < 2; ++rt) {
            const int row = wv * 32 + rt * 16 + lr;
            af[rt] = *(const bf16x8*)(L + row * 128 + (kof ^ ((row & 7) << 3)));
        }
#pragma unroll
        for (int ct = 0; ct < 8; ++ct) {
            const int row = ct * 16 + lr;     // B[k][n] = R[n][k] (symmetry)
            bfr[ct] = *(const bf16x8*)(R + row * 128 + (kof ^ ((row & 7) << 3)));
        }
#pragma unroll
        for (int rt = 0; rt < 2; ++rt)
#pragma unroll
            for (int ct = 0; ct < 8; ++ct)
                acc[rt][ct] = __builtin_amdgcn_mfma_f32_16x16x32_bf16(
                    af[rt], bfr[ct], acc[rt][ct], 0, 0, 0);
    }
}

__device__ __forceinline__ void ns_store(ushort* __restrict__ D,
                                         const f32x4 acc[2][8], int wv, int lr, int lk) {
#pragma unroll
    for (int rt = 0; rt < 2; ++rt)
#pragma unroll
        for (int ct = 0; ct < 8; ++ct)
#pragma unroll
            for (int r = 0; r < 4; ++r) {
                const int row = wv * 32 + rt * 16 + lk * 4 + r;
                const int col = ct * 16 + lr;
                D[row * 128 + (col ^ ((row & 7) << 3))] = f2bf(acc[rt][ct][r]);
            }
}

// fused transform store: D = 1.5*Ysrc - 0.5*acc   (D != Ysrc)
__device__ __forceinline__ void ns_store_t(ushort* __restrict__ D,
                                           const ushort* __restrict__ Ysrc,
                                           const f32x4 acc[2][8], int wv, int lr, int lk) {
#pragma unroll
    for (int rt = 0; rt < 2; ++rt)
#pragma unroll
        for (int ct = 0; ct < 8; ++ct)
#pragma unroll
            for (int r = 0; r < 4; ++r) {
                const int row = wv * 32 + rt * 16 + lk * 4 + r;
                const int col = ct * 16 + lr;
                const int si  = row * 128 + (col ^ ((row & 7) << 3));
                D[si] = f2bf(1.5f * bf2f(Ysrc[si]) - 0.5f * acc[rt][ct][r]);
            }
}

__global__ __launch_bounds__(256) void k_ns(const float* __restrict__ cov,
                                            const float* __restrict__ nA,
                                            const float* __restrict__ w1,
                                            const float* __restrict__ b1v,
                                            const float* __restrict__ w2,
                                            const float* __restrict__ b2v,
                                            float* __restrict__ gate) {
    __shared__ __align__(16) ushort bufs[4][16384];
    __shared__ float scol[128];
    __shared__ float sef[128];
    __shared__ float hdn[16];
    const int t = threadIdx.x;
    const int lane = t & 63, wv = t >> 6;
    const int lr = lane & 15, lk = lane >> 4;
    const int b = blockIdx.x;

    float normA = 0.f;
#pragma unroll
    for (int s = 0; s < 16; ++s) normA += nA[b * 16 + s];
    const float invn = 1.0f / normA;
    ushort* base = &bufs[0][0];

    // buf0 = A = cov/normA ; buf1 = Z1 = ZY0 = 1.5I - 0.5A   (both swizzled)
    for (int p = 0; p < 64; ++p) {
        const int idx = t + p * 256;
        const int i = idx >> 7, j = idx & 127;
        const float a = cov[(size_t)b * 16384 + idx] * invn;
        const int si = i * 128 + (j ^ ((i & 7) << 3));
        base[si]         = f2bf(a);
        base[16384 + si] = f2bf((i == j ? 1.5f : 0.f) - 0.5f * a);
    }
    __syncthreads();

    f32x4 acc[2][8];

    // Y1 = A @ ZY0 = 1.5A - 0.5*(A@A)  -> buf2
    zero_acc(acc);
    ns_mm(base, base, acc, wv, lr, lk);
    ns_store_t(base + 2 * 16384, base, acc, wv, lr, lk);
    __syncthreads();

    int y = 2, z = 1, f1 = 0, f2 = 3;
    for (int itn = 0; itn < 3; ++itn) {
        ushort* Y = base + y * 16384;
        ushort* Z = base + z * 16384;
        ushort* T = base + f1 * 16384;
        ushort* N = base + f2 * 16384;
        zero_acc(acc); ns_mm(Z, Y, acc, wv, lr, lk);     // ZY = 1.5Y - 0.5*(Z@Y)
        ns_store_t(T, Y, acc, wv, lr, lk);
        __syncthreads();
        zero_acc(acc); ns_mm(Y, T, acc, wv, lr, lk);     // Ynew = Y @ T -> N
        ns_store(N, acc, wv, lr, lk);
        zero_acc(acc); ns_mm(T, Z, acc, wv, lr, lk);     // Znew = T @ Z
        __syncthreads();
        ns_store(Y, acc, wv, lr, lk);
        __syncthreads();
        const int oy = y, oz = z, of1 = f1, of2 = f2;
        y = of2; z = oy; f1 = oz; f2 = of1;
    }

    // final: ZYf = (1.5Y - 0.5*(Y@Z)) @ Y
    {
        ushort* Y = base + y * 16384;
        ushort* Z = base + z * 16384;
        ushort* T = base + f1 * 16384;
        zero_acc(acc); ns_mm(Y, Z, acc, wv, lr, lk);
        ns_store_t(T, Y, acc, wv, lr, lk);
        __syncthreads();
        zero_acc(acc); ns_mm(T, Y, acc, wv, lr, lk);     // ZYf in regs
    }

    // column sums of ZYf  (s = colmean * sqrt(normA))
    if (t < 128) scol[t] = 0.f;
    __syncthreads();
#pragma unroll
    for (int ct = 0; ct < 8; ++ct) {
        float s = 0.f;
#pragma unroll
        for (int rt = 0; rt < 2; ++rt)
#pragma unroll
            for (int r = 0; r < 4; ++r) s += acc[rt][ct][r];
        atomicAdd(&scol[ct * 16 + lr], s);
    }
    __syncthreads();
    const float sc = sqrtf(normA) * (1.0f / 128.0f);
    if (t < 128) sef[t] = scol[t] * sc;
    __syncthreads();
    if (t < 16) {
        float a = b1v[t];
        for (int c = 0; c < 128; ++c) a += sef[c] * w1[t * 128 + c];
        hdn[t] = fmaxf(a, 0.f);
    }
    __syncthreads();
    if (t < 128) {
        float a = b2v[t];
#pragma unroll
        for (int j = 0; j < 16; ++j) a += hdn[j] * w2[t * 16 + j];
        gate[b * 128 + t] = 1.0f / (1.0f + expf(-a));
    }
}

// ---------------------------------------------------------------------------
// Kernel 4: out = gate[b,c] * x.  grid=(3, B*C); nontemporal streaming.
// ---------------------------------------------------------------------------
__global__ __launch_bounds__(256) void k_scale(const f4* __restrict__ x4,
                                               const float* __restrict__ gate,
                                               f4* __restrict__ o4) {
    const int bc = blockIdx.y;
    const float g = gate[bc];
    const int basei = bc * (MLEN / 4) + blockIdx.x * 3072 + threadIdx.x;
#pragma unroll
    for (int j = 0; j < 12; ++j) {
        const f4 v = __builtin_nontemporal_load(x4 + basei + j * 256);
        __builtin_nontemporal_store(v * g, o4 + basei + j * 256);
    }
}

// ---------------------------------------------------------------------------
extern "C" void kernel_launch(void* const* d_in, const int* in_sizes, int n_in,
                              void* d_out, int out_size, void* d_ws, size_t ws_size,
                              hipStream_t stream) {
    const float* x  = (const float*)d_in[0];
    const float* w1 = (const float*)d_in[1];
    const float* b1 = (const float*)d_in[2];
    const float* w2 = (const float*)d_in[3];
    const float* b2 = (const float*)d_in[4];
    float* out = (float*)d_out;

    char* p = (char*)d_ws;
    ushort* pG  = (ushort*)p; p += (size_t)NCH * BATCH * 16384 * 2;
    float* pR   = (float*)p;  p += (size_t)NCH * BATCH * 128 * 4;
    float* cov  = (float*)p;  p += (size_t)BATCH * 16384 * 4;
    float* nA   = (float*)p;  p += 16 * BATCH * 4;
    float* gate = (float*)p;

    k_gram<<<dim3(NCH, BATCH), 256, 0, stream>>>(x, pG, pR);
    k_cov<<<dim3(16, BATCH), 256, 0, stream>>>(pG, pR, cov, nA);
    k_ns<<<BATCH, 256, 0, stream>>>(cov, nA, w1, b1, w2, b2, gate);
    k_scale<<<dim3(3, BATCH * CHN), 256, 0, stream>>>((const f4*)x, gate, (f4*)out);
}